// Round 1
// baseline (384.695 us; speedup 1.0000x reference)
//
#include <hip/hip_runtime.h>

// ComposedFeatureTransformer: NNUE-style sparse input layer.
// out[set][b] = bias + sum_k val[set][b][k] * W[idx[set][b][k], :]
// B=4096, K=32, D=1032 (= 258 float4), W is 45056 x 1032 f32 (186 MB).

#define BATCH 4096
#define MAX_ACTIVE 32
#define DIM 1032
#define DIM4 258  // DIM / 4

__global__ __launch_bounds__(256) void ft_gather_kernel(
    const int* __restrict__ idx0, const float* __restrict__ val0,
    const int* __restrict__ idx1, const float* __restrict__ val1,
    const float* __restrict__ W, const float* __restrict__ bias,
    float* __restrict__ out)
{
    const int b   = blockIdx.x;        // 0 .. 2*BATCH-1
    const int set = b >> 12;           // BATCH = 4096 = 2^12
    const int row = b & (BATCH - 1);

    const int*   idx = set ? idx1 : idx0;
    const float* val = set ? val1 : val0;

    __shared__ int   s_idx[MAX_ACTIVE];
    __shared__ float s_val[MAX_ACTIVE];

    const int t = threadIdx.x;
    if (t < MAX_ACTIVE) {
        s_idx[t] = idx[row * MAX_ACTIVE + t];
        s_val[t] = val[row * MAX_ACTIVE + t];
    }
    __syncthreads();

    float* outp = out + (size_t)b * DIM;  // out0 then out1, concatenated flat

    for (int c = t; c < DIM4; c += 256) {
        float4 acc = ((const float4*)bias)[c];
        #pragma unroll 8
        for (int k = 0; k < MAX_ACTIVE; ++k) {
            const float4 w = ((const float4*)(W + (size_t)s_idx[k] * DIM))[c];
            const float v = s_val[k];
            acc.x += v * w.x;
            acc.y += v * w.y;
            acc.z += v * w.z;
            acc.w += v * w.w;
        }
        ((float4*)outp)[c] = acc;
    }
}

extern "C" void kernel_launch(void* const* d_in, const int* in_sizes, int n_in,
                              void* d_out, int out_size, void* d_ws, size_t ws_size,
                              hipStream_t stream) {
    const int*   idx0 = (const int*)d_in[0];
    const float* val0 = (const float*)d_in[1];
    const int*   idx1 = (const int*)d_in[2];
    const float* val1 = (const float*)d_in[3];
    const float* W    = (const float*)d_in[4];
    const float* bias = (const float*)d_in[5];
    float* out = (float*)d_out;

    dim3 grid(2 * BATCH);
    dim3 block(256);
    ft_gather_kernel<<<grid, block, 0, stream>>>(idx0, val0, idx1, val1, W, bias, out);
}